// Round 3
// baseline (380.059 us; speedup 1.0000x reference)
//
#include <hip/hip_runtime.h>
#include <hip/hip_bf16.h>

#define NWIN 256
#define NV 343
#define VPAD 352
#define NC 96
#define NH 3
#define HD 32
#define NTABLE 2197
#define SCALE_Q 0.17677669529663687f

typedef __attribute__((ext_vector_type(8))) short bf16x8;
typedef __attribute__((ext_vector_type(4))) float f32x4;

// ---- LDS layout (bytes) ----
#define OFF_Q    0                  // q_s [VPAD][32] bf16 : 22528
#define OFF_K    22528              // k_s [VPAD][32] bf16 : 22528
#define OFF_VT   45056              // v_t [32][VPAD] bf16 : 22528
#define OFF_BIAS 67584              // bias_l [2197] f32   : 8788 -> 8800
#define OFF_MC   76384              // mcode [343] i32     : 1372 -> 1376
#define OFF_U    77760              // union: {xs 64x104 bf16 (13312) + ws 96x104 bf16 (19968)} | {p_s 64x352 bf16 (45056)}
#define OFF_XS   OFF_U
#define OFF_WS   (OFF_U + 13312)
#define OFF_PS   OFF_U
#define LDS_BYTES (OFF_U + 45056)   // 122816 <= 163840

static __device__ __forceinline__ unsigned short f2b(float f) {
    union { __hip_bfloat16 b; unsigned short u; } cv;
    cv.b = __float2bfloat16(f);
    return cv.u;
}

static __device__ __forceinline__ f32x4 mfma16(bf16x8 a, bf16x8 b, f32x4 c) {
    return __builtin_amdgcn_mfma_f32_16x16x32_bf16(a, b, c, 0, 0, 0);
}

__global__ __launch_bounds__(256) void wattn(
    const float* __restrict__ x, const float* __restrict__ mask,
    const float* __restrict__ w_qkv, const float* __restrict__ bias_table,
    const int* __restrict__ rel_index, float* __restrict__ out)
{
    extern __shared__ char lds[];
    unsigned short* q_s  = (unsigned short*)(lds + OFF_Q);
    unsigned short* k_s  = (unsigned short*)(lds + OFF_K);
    unsigned short* v_t  = (unsigned short*)(lds + OFF_VT);
    float*          bias_l = (float*)(lds + OFF_BIAS);
    int*            mcode  = (int*)(lds + OFF_MC);
    unsigned short* xs   = (unsigned short*)(lds + OFF_XS);
    unsigned short* ws   = (unsigned short*)(lds + OFF_WS);
    unsigned short* p_s  = (unsigned short*)(lds + OFF_PS);

    const int tid = threadIdx.x;
    const int lane = tid & 63;
    const int wv  = tid >> 6;     // wave 0..3
    const int l15 = lane & 15;
    const int l4  = lane >> 4;    // 0..3

    // XCD swizzle: 3 heads of one window land on consecutive slots of the same XCD chunk
    int bid = blockIdx.x;
    int linear = (bid & 7) * 96 + (bid >> 3);
    int n = linear / 3;
    int h = linear - n * 3;

    // ---- stage bias LUT + linear rel-code LUT ----
    for (int i = tid; i < NTABLE; i += 256) bias_l[i] = bias_table[h * NTABLE + i];
    for (int i = tid; i < NV; i += 256) {
        int cz = i / 49; int rr = i - cz * 49; int cy = rr / 7; int cx = rr - cy * 7;
        mcode[i] = cz * 169 + cy * 13 + cx;   // rel_index(v,u) == mcode[v]-mcode[u]+1098
    }
    // ---- stage per-head W slice: rows = [q_h(32) | k_h(32) | v_h(32)], SCALE folded into q rows ----
    for (int i = tid; i < 96 * 24; i += 256) {
        int nr = i / 24, c4 = i - nr * 24;
        int g = nr >> 5, d = nr & 31;
        const float4 wq = *(const float4*)(w_qkv + (size_t)(g * NC + h * HD + d) * NC + c4 * 4);
        float s = (g == 0) ? SCALE_Q : 1.0f;
        unsigned short* dst = ws + nr * 104 + c4 * 4;
        dst[0] = f2b(wq.x * s); dst[1] = f2b(wq.y * s);
        dst[2] = f2b(wq.z * s); dst[3] = f2b(wq.w * s);
    }

    // ---- projection: qkv = x @ W^T, 64-token chunks ----
    for (int mc = 0; mc < 6; ++mc) {
        __syncthreads();
        for (int i = tid; i < 64 * 24; i += 256) {
            int r = i / 24, c4 = i - r * 24;
            int tok = mc * 64 + r;
            float4 xv = make_float4(0.f, 0.f, 0.f, 0.f);
            if (tok < NV) xv = *(const float4*)(x + ((size_t)n * NV + tok) * NC + c4 * 4);
            unsigned short* dst = xs + r * 104 + c4 * 4;
            dst[0] = f2b(xv.x); dst[1] = f2b(xv.y); dst[2] = f2b(xv.z); dst[3] = f2b(xv.w);
        }
        __syncthreads();
        int r0 = mc * 64 + wv * 16;
        if (r0 < VPAD) {
            bf16x8 a[3];
            #pragma unroll
            for (int ks = 0; ks < 3; ++ks)
                a[ks] = *(const bf16x8*)(xs + (wv * 16 + l15) * 104 + ks * 32 + l4 * 8);
            #pragma unroll
            for (int nt = 0; nt < 6; ++nt) {
                f32x4 acc = {0.f, 0.f, 0.f, 0.f};
                #pragma unroll
                for (int ks = 0; ks < 3; ++ks) {
                    bf16x8 b = *(const bf16x8*)(ws + (nt * 16 + l15) * 104 + ks * 32 + l4 * 8);
                    acc = mfma16(a[ks], b, acc);
                }
                int ch = (nt & 1) * 16 + l15;
                int t0 = r0 + l4 * 4;
                if (nt < 2) {
                    #pragma unroll
                    for (int j = 0; j < 4; ++j) q_s[(t0 + j) * 32 + ch] = f2b(acc[j]);
                } else if (nt < 4) {
                    #pragma unroll
                    for (int j = 0; j < 4; ++j) k_s[(t0 + j) * 32 + ch] = f2b(acc[j]);
                } else {
                    ushort4 pk;
                    pk.x = f2b(acc[0]); pk.y = f2b(acc[1]);
                    pk.z = f2b(acc[2]); pk.w = f2b(acc[3]);
                    *(ushort4*)(v_t + ch * VPAD + t0) = pk;   // transposed V
                }
            }
        }
    }
    __syncthreads();

    // ---- attention ----
    const float* maskn = mask + (size_t)n * NV * NV;
    for (int mc = 0; mc < 6; ++mc) {
        int r0 = mc * 64 + wv * 16;
        if (r0 >= VPAD) continue;          // no barriers below: divergence safe
        int t0 = r0 + l4 * 4;

        // prefetch mask for this chunk (issued before MFMAs to hide latency)
        float mk[22][4];
        #pragma unroll
        for (int t = 0; t < 22; ++t) {
            int u = t * 16 + l15;
            #pragma unroll
            for (int j = 0; j < 4; ++j) {
                int tok = t0 + j;
                mk[t][j] = (u < NV && tok < NV) ? maskn[(size_t)tok * NV + u] : 0.f;
            }
        }

        // QK^T : 16 rows x 352 cols per wave, K=32 -> one MFMA per tile
        bf16x8 qa = *(const bf16x8*)(q_s + (r0 + l15) * 32 + l4 * 8);
        f32x4 p[22];
        #pragma unroll
        for (int t = 0; t < 22; ++t) {
            bf16x8 kb = *(const bf16x8*)(k_s + (t * 16 + l15) * 32 + l4 * 8);
            f32x4 z = {0.f, 0.f, 0.f, 0.f};
            p[t] = mfma16(qa, kb, z);
        }

        int mv[4];
        #pragma unroll
        for (int j = 0; j < 4; ++j) {
            int tok = t0 + j;
            mv[j] = mcode[tok < NV ? tok : 0] + 1098;
        }
        float rmax[4] = {-1e30f, -1e30f, -1e30f, -1e30f};
        #pragma unroll
        for (int t = 0; t < 22; ++t) {
            int u = t * 16 + l15;
            bool uv = (u < NV);
            int mu = mcode[uv ? u : 0];
            #pragma unroll
            for (int j = 0; j < 4; ++j) {
                float val = p[t][j] + bias_l[mv[j] - mu] + mk[t][j];
                val = uv ? val : -1e30f;
                p[t][j] = val;
                rmax[j] = fmaxf(rmax[j], val);
            }
        }
        #pragma unroll
        for (int m = 1; m < 16; m <<= 1) {
            #pragma unroll
            for (int j = 0; j < 4; ++j)
                rmax[j] = fmaxf(rmax[j], __shfl_xor(rmax[j], m, 64));
        }
        float rsum[4] = {0.f, 0.f, 0.f, 0.f};
        #pragma unroll
        for (int t = 0; t < 22; ++t) {
            #pragma unroll
            for (int j = 0; j < 4; ++j) {
                float e = __expf(p[t][j] - rmax[j]);
                rsum[j] += e;
                p_s[(wv * 16 + l4 * 4 + j) * VPAD + t * 16 + l15] = f2b(e);
            }
        }
        #pragma unroll
        for (int m = 1; m < 16; m <<= 1) {
            #pragma unroll
            for (int j = 0; j < 4; ++j)
                rsum[j] += __shfl_xor(rsum[j], m, 64);
        }

        // AV : rows are per-wave private in p_s -> no barrier needed
        f32x4 o0 = {0.f,0.f,0.f,0.f}, o1 = {0.f,0.f,0.f,0.f};
        #pragma unroll
        for (int ks = 0; ks < 11; ++ks) {
            bf16x8 pa  = *(const bf16x8*)(p_s + (wv * 16 + l15) * VPAD + ks * 32 + l4 * 8);
            bf16x8 vb0 = *(const bf16x8*)(v_t + l15 * VPAD + ks * 32 + l4 * 8);
            bf16x8 vb1 = *(const bf16x8*)(v_t + (16 + l15) * VPAD + ks * 32 + l4 * 8);
            o0 = mfma16(pa, vb0, o0);
            o1 = mfma16(pa, vb1, o1);
        }
        #pragma unroll
        for (int j = 0; j < 4; ++j) {
            int tok = t0 + j;
            if (tok < NV) {
                float inv = 1.0f / rsum[j];
                float* op = out + ((size_t)n * NV + tok) * NC + h * HD;
                op[l15]      = o0[j] * inv;
                op[16 + l15] = o1[j] * inv;
            }
        }
    }
}

extern "C" void kernel_launch(void* const* d_in, const int* in_sizes, int n_in,
                              void* d_out, int out_size, void* d_ws, size_t ws_size,
                              hipStream_t stream) {
    const float* x          = (const float*)d_in[0];
    const float* mask       = (const float*)d_in[1];
    const float* w_qkv      = (const float*)d_in[2];
    const float* bias_table = (const float*)d_in[3];
    const int*   rel_index  = (const int*)d_in[4];
    float* out = (float*)d_out;

    (void)rel_index; (void)in_sizes; (void)n_in; (void)out_size; (void)d_ws; (void)ws_size;

    // allow >64KB dynamic LDS (no-op if already set; capture-safe, not stream-ordered)
    hipFuncSetAttribute((const void*)wattn, hipFuncAttributeMaxDynamicSharedMemorySize, LDS_BYTES);

    wattn<<<dim3(NWIN * NH), dim3(256), LDS_BYTES, stream>>>(x, mask, w_qkv, bias_table, rel_index, out);
}